// Round 1
// baseline (10198.859 us; speedup 1.0000x reference)
//
#include <hip/hip_runtime.h>
#include <cmath>

#define QLEN 300
#define BATCH 16
#define SLEN 1024
#define DM 256
#define DD 512
#define FFND 1024
#define NQROWS (QLEN*BATCH)   // 4800
#define NMROWS (SLEN*BATCH)   // 16384

__device__ __forceinline__ float sigmoidf_(float x){ return 1.f/(1.f+expf(-x)); }

// ---------------- generic GEMM: C[M,N] = act((A(+A2)) @ W[K,N] + bias) ----------------
// A: [M,K] with row stride lda. W row-major [K,N]. M%64==0, N%64==0, K%16==0.
__global__ __launch_bounds__(256) void gemm_f32(
    const float* __restrict__ A, const float* __restrict__ A2,
    const float* __restrict__ W, const float* __restrict__ bias,
    float* __restrict__ C, int M, int N, int K, int lda, int relu)
{
  __shared__ __align__(16) float As[16][68];  // [k][m]
  __shared__ __align__(16) float Bs[16][68];  // [k][n]
  const int tid = threadIdx.x;
  const int bm = blockIdx.y * 64, bn = blockIdx.x * 64;
  const int tx = tid & 15, ty = tid >> 4;
  const int ar = tid >> 4, ac = tid & 15;     // A-tile loader coords
  const int bk = tid >> 6, bnn = tid & 63;    // B-tile loader coords
  float acc[4][4] = {};
  for (int k0 = 0; k0 < K; k0 += 16) {
    #pragma unroll
    for (int i = 0; i < 4; ++i) {
      int row = ar + i*16;
      float v = A[(size_t)(bm+row)*lda + (k0+ac)];
      if (A2) v += A2[(size_t)(bm+row)*lda + (k0+ac)];
      As[ac][row] = v;
    }
    #pragma unroll
    for (int i = 0; i < 4; ++i) {
      int kk = bk + i*4;
      Bs[kk][bnn] = W[(size_t)(k0+kk)*N + (bn+bnn)];
    }
    __syncthreads();
    #pragma unroll
    for (int k = 0; k < 16; ++k) {
      float4 a4 = *reinterpret_cast<const float4*>(&As[k][ty*4]);
      float4 b4 = *reinterpret_cast<const float4*>(&Bs[k][tx*4]);
      float a[4] = {a4.x,a4.y,a4.z,a4.w};
      float b[4] = {b4.x,b4.y,b4.z,b4.w};
      #pragma unroll
      for (int i=0;i<4;++i)
        #pragma unroll
        for (int j=0;j<4;++j)
          acc[i][j] = fmaf(a[i], b[j], acc[i][j]);
    }
    __syncthreads();
  }
  float vb[4] = {0.f,0.f,0.f,0.f};
  if (bias) {
    float4 b4 = *reinterpret_cast<const float4*>(&bias[bn + tx*4]);
    vb[0]=b4.x; vb[1]=b4.y; vb[2]=b4.z; vb[3]=b4.w;
  }
  #pragma unroll
  for (int i=0;i<4;++i) {
    int row = bm + ty*4 + i;
    float r0 = acc[i][0]+vb[0], r1 = acc[i][1]+vb[1], r2 = acc[i][2]+vb[2], r3 = acc[i][3]+vb[3];
    if (relu){ r0=fmaxf(r0,0.f); r1=fmaxf(r1,0.f); r2=fmaxf(r2,0.f); r3=fmaxf(r3,0.f); }
    float4 o; o.x=r0; o.y=r1; o.z=r2; o.w=r3;
    *reinterpret_cast<float4*>(&C[(size_t)row*N + bn + tx*4]) = o;
  }
}

// ---------------- skinny GEMM (N=2 or 4): one wave per row ----------------
__global__ __launch_bounds__(256) void gemm_skinny(
    const float* __restrict__ A, const float* __restrict__ W, const float* __restrict__ bias,
    float* __restrict__ C, int M, int N, int K, int lda)
{
  int wid = threadIdx.x >> 6, lane = threadIdx.x & 63;
  int row = blockIdx.x * 4 + wid;
  if (row >= M) return;
  float acc[4] = {0.f,0.f,0.f,0.f};
  for (int k = lane; k < K; k += 64) {
    float av = A[(size_t)row*lda + k];
    for (int n = 0; n < N; ++n) acc[n] += av * W[(size_t)k*N + n];
  }
  for (int off = 32; off; off >>= 1)
    for (int n = 0; n < N; ++n) acc[n] += __shfl_down(acc[n], off);
  if (lane == 0)
    for (int n = 0; n < N; ++n) C[(size_t)row*N + n] = acc[n] + bias[n];
}

// ---------------- sine positional embedding (loop-invariant) ----------------
// refb: [NQROWS,2] pre-sigmoid. out: [NQROWS,256]; ch 0..127 from y, 128..255 from x.
__global__ void sine_embed_kernel(const float* __restrict__ refb, float* __restrict__ sine)
{
  int idx = blockIdx.x*blockDim.x + threadIdx.x;
  if (idx >= NQROWS*DM) return;
  int r = idx >> 8, c = idx & 255;
  int j = c & 127;
  float coord = refb[r*2 + (c < 128 ? 1 : 0)];
  float s = sigmoidf_(coord);
  float freq = expf(-(float)(j >> 1) * (9.210340371976184f / 64.f)); // 10000^{-(j>>1)/64}
  float v = s * 6.283185307179586f * freq;
  sine[idx] = (j & 1) ? cosf(v) : sinf(v);
}

// ---------------- boxes + cs from bbox-MLP output ----------------
__global__ void boxes_kernel(const float* __restrict__ t4, const float* __restrict__ refb,
                             float* __restrict__ boxes, float* __restrict__ cs)
{
  int idx = blockIdx.x*blockDim.x + threadIdx.x;
  if (idx >= NQROWS) return;
  int q = idx / BATCH, b = idx % BATCH;
  float cx = sigmoidf_(t4[idx*4+0] + refb[idx*2+0]);
  float cy = sigmoidf_(t4[idx*4+1] + refb[idx*2+1]);
  float w  = sigmoidf_(t4[idx*4+2]);
  float h  = sigmoidf_(t4[idx*4+3]);
  int o = b*QLEN + q;
  boxes[o*4+0] = cx - 0.5f*w;
  boxes[o*4+1] = cy - 0.5f*h;
  boxes[o*4+2] = cx + 0.5f*w;
  boxes[o*4+3] = cy + 0.5f*h;
  cs[o] = cx + cy;
}

// ---------------- bias[b,i,j] = IoU(box_i,box_j) + (cs_i > cs_j) ----------------
__global__ void bias_kernel(const float* __restrict__ boxes, const float* __restrict__ cs,
                            float* __restrict__ bias)
{
  int idx = blockIdx.x*blockDim.x + threadIdx.x;
  const int QQ = QLEN*QLEN;
  if (idx >= BATCH*QQ) return;
  int b = idx / QQ, rem = idx - b*QQ;
  int i = rem / QLEN, j = rem - i*QLEN;
  float4 bi = *reinterpret_cast<const float4*>(&boxes[((size_t)b*QLEN + i)*4]);
  float4 bj = *reinterpret_cast<const float4*>(&boxes[((size_t)b*QLEN + j)*4]);
  float ai = (bi.z-bi.x)*(bi.w-bi.y);
  float aj = (bj.z-bj.x)*(bj.w-bj.y);
  float ltx = fmaxf(bi.x, bj.x), lty = fmaxf(bi.y, bj.y);
  float rbx = fminf(bi.z, bj.z), rby = fminf(bi.w, bj.w);
  float w = fmaxf(rbx-ltx, 0.f), h = fmaxf(rby-lty, 0.f);
  float inter = w*h;
  float iou = inter / (ai + aj - inter);
  bias[idx] = iou + ((cs[b*QLEN+i] > cs[b*QLEN+j]) ? 1.f : 0.f);
}

// ---------------- elementwise: QSA = X + qp2 ----------------
__global__ void add_qp2(const float* __restrict__ X, const float* __restrict__ qp,
                        float* __restrict__ out)
{
  int idx = blockIdx.x*blockDim.x + threadIdx.x;
  if (idx >= NQROWS*DD) return;
  int r = idx >> 9, c = idx & 511;
  out[idx] = X[idx] + qp[(r<<8) + (c & 255)];
}

// ---------------- elementwise: CAQ = X + qp2 + (sine*pt)2 ----------------
__global__ void caq_kernel(const float* __restrict__ X, const float* __restrict__ qp,
                           const float* __restrict__ sine, const float* __restrict__ pt,
                           float* __restrict__ out)
{
  int idx = blockIdx.x*blockDim.x + threadIdx.x;
  if (idx >= NQROWS*DD) return;
  int r = idx >> 9, c = idx & 511;
  int c2 = (r<<8) + (c & 255);
  out[idx] = X[idx] + qp[c2] + sine[c2]*pt[c2];
}

// ---------------- fused residual + LayerNorm (eps=1e-5, no affine), in-place on X ----------------
__global__ __launch_bounds__(256) void ln_residual(float* __restrict__ X, const float* __restrict__ Y)
{
  int row = blockIdx.x, tid = threadIdx.x;
  size_t base = (size_t)row*DD;
  float v0 = X[base+tid]     + Y[base+tid];
  float v1 = X[base+tid+256] + Y[base+tid+256];
  float s = v0+v1, sq = v0*v0+v1*v1;
  for (int off = 32; off; off >>= 1) { s += __shfl_down(s,off); sq += __shfl_down(sq,off); }
  __shared__ float ss[4], ssq[4];
  int wid = tid>>6, lane = tid&63;
  if (lane==0){ ss[wid]=s; ssq[wid]=sq; }
  __syncthreads();
  if (tid==0){
    float a=ss[0]+ss[1]+ss[2]+ss[3], b=ssq[0]+ssq[1]+ssq[2]+ssq[3];
    float mean = a*(1.f/DD);
    float var  = b*(1.f/DD) - mean*mean;
    ss[0]=mean; ssq[0]=rsqrtf(fmaxf(var,0.f)+1e-5f);
  }
  __syncthreads();
  float mean = ss[0], inv = ssq[0];
  X[base+tid]     = (v0-mean)*inv;
  X[base+tid+256] = (v1-mean)*inv;
}

__global__ void copy_f32(const float* __restrict__ src, float* __restrict__ dst, int n)
{
  int idx = blockIdx.x*blockDim.x + threadIdx.x;
  if (idx < n) dst[idx] = src[idx];
}

// ---------------- fused attention (flash-style, online softmax) ----------------
// Qp:[Lq*B,512] row=q*B+b, Kp/Vp:[Lk*B,512], head h -> cols h*64..h*64+63.
// bias (optional): [B,Lq,Lk]. O: [Lq*B,512]. grid: (ceil(Lq/16), B*8). block 256.
__global__ __launch_bounds__(256) void attn_f32(
    const float* __restrict__ Qp, const float* __restrict__ Kp, const float* __restrict__ Vp,
    const float* __restrict__ bias, float* __restrict__ O, int Lq, int Lk)
{
  __shared__ __align__(16) float Qs[16][65];
  __shared__ __align__(16) float Ks[64][65];
  __shared__ __align__(16) float Vs[64][68];
  __shared__ __align__(16) float Ps[16][68];
  const int tid = threadIdx.x;
  const int h = blockIdx.y & 7, b = blockIdx.y >> 3;
  const int qt = blockIdx.x * 16;
  #pragma unroll
  for (int i = 0; i < 4; ++i) {
    int idx = tid + i*256, row = idx >> 6, col = idx & 63;
    int qrow = qt + row;
    Qs[row][col] = (qrow < Lq) ? Qp[((size_t)qrow*BATCH + b)*DD + h*64 + col] : 0.f;
  }
  const int qi = tid >> 4, tj = tid & 15, c0 = tj*4;
  const int qglob = qt + qi;
  float m = -INFINITY, lsum = 0.f;
  float acc0=0.f, acc1=0.f, acc2=0.f, acc3=0.f;
  __syncthreads();
  for (int kt = 0; kt < Lk; kt += 64) {
    #pragma unroll
    for (int i = 0; i < 16; ++i) {
      int idx = tid + i*256, row = idx >> 6, col = idx & 63;
      int krow = kt + row;
      float kv = 0.f, vv = 0.f;
      if (krow < Lk) {
        size_t g = ((size_t)krow*BATCH + b)*DD + h*64 + col;
        kv = Kp[g]; vv = Vp[g];
      }
      Ks[row][col] = kv; Vs[row][col] = vv;
    }
    __syncthreads();
    float sv[4] = {0.f,0.f,0.f,0.f};
    #pragma unroll 16
    for (int dd = 0; dd < 64; ++dd) {
      float qv = Qs[qi][dd];
      #pragma unroll
      for (int jj = 0; jj < 4; ++jj)
        sv[jj] = fmaf(qv, Ks[tj*4+jj][dd], sv[jj]);
    }
    #pragma unroll
    for (int jj = 0; jj < 4; ++jj) {
      int kglob = kt + tj*4 + jj;
      if (kglob < Lk) {
        sv[jj] *= 0.125f;
        if (bias && qglob < Lq) sv[jj] += bias[((size_t)b*Lq + qglob)*Lk + kglob];
      } else sv[jj] = -INFINITY;
    }
    float tmax = fmaxf(fmaxf(sv[0],sv[1]), fmaxf(sv[2],sv[3]));
    #pragma unroll
    for (int off = 8; off; off >>= 1) tmax = fmaxf(tmax, __shfl_xor(tmax, off, 16));
    float newm = fmaxf(m, tmax);
    float corr = expf(m - newm);   // m=-inf on first tile -> corr=0
    float psum = 0.f;
    #pragma unroll
    for (int jj = 0; jj < 4; ++jj) {
      float p = expf(sv[jj] - newm);
      psum += p;
      Ps[qi][tj*4+jj] = p;
    }
    #pragma unroll
    for (int off = 8; off; off >>= 1) psum += __shfl_xor(psum, off, 16);
    lsum = lsum*corr + psum;
    acc0 *= corr; acc1 *= corr; acc2 *= corr; acc3 *= corr;
    m = newm;
    __syncthreads();  // Ps visible to all row threads
    #pragma unroll 16
    for (int kj = 0; kj < 64; ++kj) {
      float p = Ps[qi][kj];
      float4 vv = *reinterpret_cast<const float4*>(&Vs[kj][c0]);
      acc0 = fmaf(p, vv.x, acc0); acc1 = fmaf(p, vv.y, acc1);
      acc2 = fmaf(p, vv.z, acc2); acc3 = fmaf(p, vv.w, acc3);
    }
    __syncthreads();
  }
  if (qglob < Lq) {
    float inv = 1.f / lsum;
    float4 o; o.x=acc0*inv; o.y=acc1*inv; o.z=acc2*inv; o.w=acc3*inv;
    *reinterpret_cast<float4*>(&O[((size_t)qglob*BATCH + b)*DD + h*64 + c0]) = o;
  }
}

extern "C" void kernel_launch(void* const* d_in, const int* in_sizes, int n_in,
                              void* d_out, int out_size, void* d_ws, size_t ws_size,
                              hipStream_t stream)
{
  const float* tgt       = (const float*)d_in[0];
  const float* memory    = (const float*)d_in[1];
  const float* pos       = (const float*)d_in[2];
  const float* query_pos = (const float*)d_in[3];
  const float* qs_W1 = (const float*)d_in[4];  const float* qs_b1 = (const float*)d_in[5];
  const float* qs_W2 = (const float*)d_in[6];  const float* qs_b2 = (const float*)d_in[7];
  const float* rp_W1 = (const float*)d_in[8];  const float* rp_b1 = (const float*)d_in[9];
  const float* rp_W2 = (const float*)d_in[10]; const float* rp_b2 = (const float*)d_in[11];
  const float* bb_W1 = (const float*)d_in[12]; const float* bb_b1 = (const float*)d_in[13];
  const float* bb_W2 = (const float*)d_in[14]; const float* bb_b2 = (const float*)d_in[15];
  const float* sa_Wq = (const float*)d_in[16]; const float* sa_Wk = (const float*)d_in[17];
  const float* sa_Wv = (const float*)d_in[18]; const float* sa_Wo = (const float*)d_in[19];
  const float* ca_Wq = (const float*)d_in[20]; const float* ca_Wk = (const float*)d_in[21];
  const float* ca_Wv = (const float*)d_in[22]; const float* ca_Wo = (const float*)d_in[23];
  const float* ff_W1 = (const float*)d_in[24]; const float* ff_b1 = (const float*)d_in[25];
  const float* ff_W2 = (const float*)d_in[26]; const float* ff_b2 = (const float*)d_in[27];

  float* Wsp = (float*)d_ws;
  size_t o = 0;
  float* X    = Wsp + o; o += (size_t)NQROWS*DD;
  float* SINE = Wsp + o; o += (size_t)NQROWS*DM;
  float* PT   = Wsp + o; o += (size_t)NQROWS*DM;
  float* T256 = Wsp + o; o += (size_t)NQROWS*DM;
  float* REFB = Wsp + o; o += (size_t)NQROWS*2;
  float* T4   = Wsp + o; o += (size_t)NQROWS*4;
  float* BOX  = Wsp + o; o += (size_t)NQROWS*4;
  float* CS   = Wsp + o; o += (size_t)NQROWS;
  float* BIAS = Wsp + o; o += (size_t)BATCH*QLEN*QLEN;
  float* QSA  = Wsp + o; o += (size_t)NQROWS*DD;   // also attention output AO
  float* PQ   = Wsp + o; o += (size_t)NQROWS*DD;   // also Wo-output / FFN-output
  float* PK   = Wsp + o; o += (size_t)NMROWS*DD;   // also FFN hidden
  float* PV   = Wsp + o; o += (size_t)NMROWS*DD;
  if (ws_size < o * sizeof(float)) return;  // workspace too small: bail

  dim3 B256(256);
  auto gemm = [&](const float* A, const float* A2, const float* Wt, const float* bs,
                  float* C, int M, int N, int K, int lda, int relu) {
    dim3 grid(N/64, M/64);
    hipLaunchKernelGGL(gemm_f32, grid, B256, 0, stream, A, A2, Wt, bs, C, M, N, K, lda, relu);
  };

  const int nTotal = NQROWS*DD;
  // ---- pre-loop (loop-invariant) ----
  hipLaunchKernelGGL(copy_f32, dim3((nTotal+255)/256), B256, 0, stream, tgt, X, nTotal);
  gemm(query_pos, nullptr, rp_W1, rp_b1, T256, NQROWS, DM, DM, DM, 1);
  hipLaunchKernelGGL(gemm_skinny, dim3(NQROWS/4), B256, 0, stream, T256, rp_W2, rp_b2, REFB, NQROWS, 2, DM, DM);
  hipLaunchKernelGGL(sine_embed_kernel, dim3((NQROWS*DM+255)/256), B256, 0, stream, REFB, SINE);

  for (int l = 0; l < 6; ++l) {
    const float* sWq = sa_Wq + (size_t)l*DD*DD;  const float* sWk = sa_Wk + (size_t)l*DD*DD;
    const float* sWv = sa_Wv + (size_t)l*DD*DD;  const float* sWo = sa_Wo + (size_t)l*DD*DD;
    const float* cWq = ca_Wq + (size_t)l*DD*DD;  const float* cWk = ca_Wk + (size_t)l*DD*DD;
    const float* cWv = ca_Wv + (size_t)l*DD*DD;  const float* cWo = ca_Wo + (size_t)l*DD*DD;
    const float* fW1 = ff_W1 + (size_t)l*DD*FFND; const float* fb1 = ff_b1 + (size_t)l*FFND;
    const float* fW2 = ff_W2 + (size_t)l*FFND*DD; const float* fb2 = ff_b2 + (size_t)l*DD;

    // pos_transform = MLP(X[:,256:]); qs folded in later via caq_kernel
    gemm(X+DM, nullptr, qs_W1, qs_b1, T256, NQROWS, DM, DM, DD, 1);
    gemm(T256, nullptr, qs_W2, qs_b2, PT,   NQROWS, DM, DM, DM, 0);
    // bbox MLP -> boxes -> iou+order bias
    gemm(X+DM, nullptr, bb_W1, bb_b1, T256, NQROWS, DM, DM, DD, 1);
    hipLaunchKernelGGL(gemm_skinny, dim3(NQROWS/4), B256, 0, stream, T256, bb_W2, bb_b2, T4, NQROWS, 4, DM, DM);
    hipLaunchKernelGGL(boxes_kernel, dim3((NQROWS+255)/256), B256, 0, stream, T4, REFB, BOX, CS);
    hipLaunchKernelGGL(bias_kernel, dim3((BATCH*QLEN*QLEN+255)/256), B256, 0, stream, BOX, CS, BIAS);

    // ---- self-attention ----
    hipLaunchKernelGGL(add_qp2, dim3((nTotal+255)/256), B256, 0, stream, X, query_pos, QSA);
    gemm(QSA, nullptr, sWq, nullptr, PQ, NQROWS, DD, DD, DD, 0);
    gemm(QSA, nullptr, sWk, nullptr, PK, NQROWS, DD, DD, DD, 0);
    gemm(X,   nullptr, sWv, nullptr, PV, NQROWS, DD, DD, DD, 0);
    hipLaunchKernelGGL(attn_f32, dim3((QLEN+15)/16, BATCH*8), B256, 0, stream, PQ, PK, PV, BIAS, QSA, QLEN, QLEN);
    gemm(QSA, nullptr, sWo, nullptr, PQ, NQROWS, DD, DD, DD, 0);
    hipLaunchKernelGGL(ln_residual, dim3(NQROWS), B256, 0, stream, X, PQ);

    // ---- cross-attention ----
    hipLaunchKernelGGL(caq_kernel, dim3((nTotal+255)/256), B256, 0, stream, X, query_pos, SINE, PT, QSA);
    gemm(QSA, nullptr, cWq, nullptr, PQ, NQROWS, DD, DD, DD, 0);
    gemm(memory, pos,     cWk, nullptr, PK, NMROWS, DD, DD, DD, 0);
    gemm(memory, nullptr, cWv, nullptr, PV, NMROWS, DD, DD, DD, 0);
    hipLaunchKernelGGL(attn_f32, dim3((QLEN+15)/16, BATCH*8), B256, 0, stream, PQ, PK, PV, (const float*)nullptr, QSA, QLEN, SLEN);
    gemm(QSA, nullptr, cWo, nullptr, PQ, NQROWS, DD, DD, DD, 0);
    hipLaunchKernelGGL(ln_residual, dim3(NQROWS), B256, 0, stream, X, PQ);

    // ---- FFN ----
    gemm(X,  nullptr, fW1, fb1, PK, NQROWS, FFND, DD, DD, 1);   // hidden (aliases PK)
    gemm(PK, nullptr, fW2, fb2, PQ, NQROWS, DD, FFND, FFND, 0);
    hipLaunchKernelGGL(ln_residual, dim3(NQROWS), B256, 0, stream, X, PQ);
  }

  hipLaunchKernelGGL(copy_f32, dim3((nTotal+255)/256), B256, 0, stream, X, (float*)d_out, out_size);
}

// Round 2
// 3051.425 us; speedup vs baseline: 3.3423x; 3.3423x over previous
//
#include <hip/hip_runtime.h>
#include <cmath>

#define QLEN 300
#define BATCH 16
#define SLEN 1024
#define DM 256
#define DD 512
#define FFND 1024
#define NQROWS (QLEN*BATCH)   // 4800
#define NMROWS (SLEN*BATCH)   // 16384

typedef __attribute__((ext_vector_type(8))) short short8;
typedef __attribute__((ext_vector_type(4))) float f32x4;

__device__ __forceinline__ float sigmoidf_(float x){ return 1.f/(1.f+expf(-x)); }

__device__ __forceinline__ unsigned short f2bf(float x){
  unsigned u = __float_as_uint(x);
  unsigned r = (u + 0x7FFFu + ((u >> 16) & 1u)) >> 16;
  return (unsigned short)r;
}

// ================= weight transpose + f32->bf16 : W[K,N] -> Wt[N,K] =================
__global__ __launch_bounds__(256) void transpose_cvt(
    const float* __restrict__ W, unsigned short* __restrict__ Wt, int K, int N)
{
  __shared__ float T[32][33];
  int n0 = blockIdx.x*32, k0 = blockIdx.y*32;
  size_t zo = (size_t)blockIdx.z * K * N;
  int tx = threadIdx.x & 31, ty = threadIdx.x >> 5;
  #pragma unroll
  for (int j = 0; j < 32; j += 8)
    T[ty+j][tx] = W[zo + (size_t)(k0+ty+j)*N + n0+tx];
  __syncthreads();
  #pragma unroll
  for (int j = 0; j < 32; j += 8)
    Wt[zo + (size_t)(n0+ty+j)*K + k0+tx] = f2bf(T[tx][ty+j]);
}

// ================= bf16 MFMA GEMM: C[M,N] = act(A @ Wt^T + bias) =================
// A: AMODE 0: bf16 [M,*lda]; 1: f32; 2: f32 A+A2. Wt: bf16 [N,K]. 64x64 tile, BK=64.
template<int AMODE, bool OUTBF16, bool RELU>
__global__ __launch_bounds__(256) void gemm_mfma(
    const void* __restrict__ Aptr, const float* __restrict__ A2,
    const unsigned short* __restrict__ Wt, const float* __restrict__ bias,
    void* __restrict__ Cptr, int M, int N, int K, int lda)
{
  __shared__ __align__(16) unsigned short As[64][72];
  __shared__ __align__(16) unsigned short Bs[64][72];
  const int tid = threadIdx.x;
  const int bm = blockIdx.y*64, bn = blockIdx.x*64;
  const int w = tid >> 6, lane = tid & 63;
  const int wm = w >> 1, wn = w & 1;
  const int c = lane & 15, hi = lane >> 4;
  const int sr = tid >> 3, sk = (tid & 7) * 8;
  f32x4 acc[2][2] = {};
  for (int k0 = 0; k0 < K; k0 += 64) {
    #pragma unroll
    for (int it = 0; it < 2; ++it) {
      int m = sr + it*32;
      if (AMODE == 0) {
        const unsigned short* Ab = (const unsigned short*)Aptr;
        short8 v = *reinterpret_cast<const short8*>(&Ab[(size_t)(bm+m)*lda + k0 + sk]);
        *reinterpret_cast<short8*>(&As[m][sk]) = v;
      } else {
        const float* Af = (const float*)Aptr;
        size_t base = (size_t)(bm+m)*lda + k0 + sk;
        float4 f0 = *reinterpret_cast<const float4*>(&Af[base]);
        float4 f1 = *reinterpret_cast<const float4*>(&Af[base+4]);
        if (AMODE == 2) {
          float4 g0 = *reinterpret_cast<const float4*>(&A2[base]);
          float4 g1 = *reinterpret_cast<const float4*>(&A2[base+4]);
          f0.x+=g0.x; f0.y+=g0.y; f0.z+=g0.z; f0.w+=g0.w;
          f1.x+=g1.x; f1.y+=g1.y; f1.z+=g1.z; f1.w+=g1.w;
        }
        short8 v;
        v[0]=(short)f2bf(f0.x); v[1]=(short)f2bf(f0.y); v[2]=(short)f2bf(f0.z); v[3]=(short)f2bf(f0.w);
        v[4]=(short)f2bf(f1.x); v[5]=(short)f2bf(f1.y); v[6]=(short)f2bf(f1.z); v[7]=(short)f2bf(f1.w);
        *reinterpret_cast<short8*>(&As[m][sk]) = v;
      }
      short8 bv = *reinterpret_cast<const short8*>(&Wt[(size_t)(bn+m)*K + k0 + sk]);
      *reinterpret_cast<short8*>(&Bs[m][sk]) = bv;
    }
    __syncthreads();
    #pragma unroll
    for (int ks = 0; ks < 2; ++ks) {
      short8 a0 = *reinterpret_cast<const short8*>(&As[wm*32 + c][ks*32 + hi*8]);
      short8 a1 = *reinterpret_cast<const short8*>(&As[wm*32 + 16 + c][ks*32 + hi*8]);
      short8 b0 = *reinterpret_cast<const short8*>(&Bs[wn*32 + c][ks*32 + hi*8]);
      short8 b1 = *reinterpret_cast<const short8*>(&Bs[wn*32 + 16 + c][ks*32 + hi*8]);
      acc[0][0] = __builtin_amdgcn_mfma_f32_16x16x32_bf16(a0, b0, acc[0][0], 0, 0, 0);
      acc[0][1] = __builtin_amdgcn_mfma_f32_16x16x32_bf16(a0, b1, acc[0][1], 0, 0, 0);
      acc[1][0] = __builtin_amdgcn_mfma_f32_16x16x32_bf16(a1, b0, acc[1][0], 0, 0, 0);
      acc[1][1] = __builtin_amdgcn_mfma_f32_16x16x32_bf16(a1, b1, acc[1][1], 0, 0, 0);
    }
    __syncthreads();
  }
  #pragma unroll
  for (int mf = 0; mf < 2; ++mf) {
    #pragma unroll
    for (int nf = 0; nf < 2; ++nf) {
      int colg = bn + wn*32 + nf*16 + c;
      float bv = bias ? bias[colg] : 0.f;
      #pragma unroll
      for (int r = 0; r < 4; ++r) {
        int rowg = bm + wm*32 + mf*16 + hi*4 + r;
        float v = acc[mf][nf][r] + bv;
        if (RELU) v = fmaxf(v, 0.f);
        if (OUTBF16) ((unsigned short*)Cptr)[(size_t)rowg*N + colg] = f2bf(v);
        else         ((float*)Cptr)[(size_t)rowg*N + colg] = v;
      }
    }
  }
}

// ================= MFMA flash attention =================
// Qp/Kp/Vp bf16 [L*B,512] row = l*B+b; head h -> cols h*64..+63. bias f32 [B,Lq,Lk].
// Ob bf16. grid: (ceil(Lq/64), B*8), block 256 (4 waves, 16 q-rows each).
template<bool HAS_BIAS>
__global__ __launch_bounds__(256) void attn_mfma(
    const unsigned short* __restrict__ Qp, const unsigned short* __restrict__ Kp,
    const unsigned short* __restrict__ Vp, const float* __restrict__ bias,
    unsigned short* __restrict__ Ob, int Lq, int Lk)
{
  __shared__ __align__(16) unsigned short Ks[64][72];
  __shared__ __align__(16) unsigned short Pl[4][16][72];
  const int tid = threadIdx.x;
  const int w = tid >> 6, lane = tid & 63;
  const int c = lane & 15, hi = lane >> 4;
  const int h = blockIdx.y & 7, b = blockIdx.y >> 3;
  const int qt = blockIdx.x * 64;
  const int hb = h * 64;

  int qrow = qt + w*16 + c; if (qrow > Lq-1) qrow = Lq-1;
  const unsigned short* qptr = Qp + ((size_t)qrow*BATCH + b)*DD + hb;
  short8 qf0 = *reinterpret_cast<const short8*>(qptr + hi*8);
  short8 qf1 = *reinterpret_cast<const short8*>(qptr + 32 + hi*8);

  float m_[4], l_[4];
  f32x4 accO[4] = {};
  #pragma unroll
  for (int r = 0; r < 4; ++r) { m_[r] = -1e30f; l_[r] = 0.f; }

  const int sr = tid >> 3, skk = (tid & 7) * 8;
  const int qbase = qt + w*16 + hi*4;
  const int nt = (Lk + 63) >> 6;
  for (int t = 0; t < nt; ++t) {
    const int kt = t * 64;
    #pragma unroll
    for (int it = 0; it < 2; ++it) {
      int kr = kt + sr + it*32; if (kr > Lk-1) kr = Lk-1;
      short8 v = *reinterpret_cast<const short8*>(&Kp[((size_t)kr*BATCH + b)*DD + hb + skk]);
      *reinterpret_cast<short8*>(&Ks[sr + it*32][skk]) = v;
    }
    __syncthreads();
    // S = Q K^T
    f32x4 s[4] = {};
    #pragma unroll
    for (int g = 0; g < 4; ++g) {
      short8 kb0 = *reinterpret_cast<const short8*>(&Ks[g*16 + c][hi*8]);
      short8 kb1 = *reinterpret_cast<const short8*>(&Ks[g*16 + c][32 + hi*8]);
      s[g] = __builtin_amdgcn_mfma_f32_16x16x32_bf16(qf0, kb0, s[g], 0, 0, 0);
      s[g] = __builtin_amdgcn_mfma_f32_16x16x32_bf16(qf1, kb1, s[g], 0, 0, 0);
    }
    // logits + mask + bias; lane holds S[q=hi*4+r][key=c+16g]
    float p[4][4];
    float tmax[4] = {-1e30f, -1e30f, -1e30f, -1e30f};
    #pragma unroll
    for (int g = 0; g < 4; ++g) {
      int kg = kt + g*16 + c;
      bool kvalid = kg < Lk;
      int kgc = kvalid ? kg : Lk-1;
      #pragma unroll
      for (int r = 0; r < 4; ++r) {
        float v = s[g][r] * 0.125f;
        if (HAS_BIAS) {
          int qg = qbase + r; if (qg > Lq-1) qg = Lq-1;
          v += bias[((size_t)b*Lq + qg)*Lk + kgc];
        }
        if (!kvalid) v = -1e30f;
        p[g][r] = v;
        tmax[r] = fmaxf(tmax[r], v);
      }
    }
    float corr[4], newm[4];
    #pragma unroll
    for (int r = 0; r < 4; ++r) {
      float tm = tmax[r];
      tm = fmaxf(tm, __shfl_xor(tm, 1));
      tm = fmaxf(tm, __shfl_xor(tm, 2));
      tm = fmaxf(tm, __shfl_xor(tm, 4));
      tm = fmaxf(tm, __shfl_xor(tm, 8));
      newm[r] = fmaxf(m_[r], tm);
      corr[r] = expf(m_[r] - newm[r]);
      m_[r] = newm[r];
    }
    float psum[4] = {0.f, 0.f, 0.f, 0.f};
    #pragma unroll
    for (int g = 0; g < 4; ++g)
      #pragma unroll
      for (int r = 0; r < 4; ++r) {
        float e = expf(p[g][r] - newm[r]);
        psum[r] += e;
        Pl[w][hi*4 + r][c + 16*g] = f2bf(e);
      }
    #pragma unroll
    for (int r = 0; r < 4; ++r) {
      float ps = psum[r];
      ps += __shfl_xor(ps, 1);
      ps += __shfl_xor(ps, 2);
      ps += __shfl_xor(ps, 4);
      ps += __shfl_xor(ps, 8);
      l_[r] = l_[r]*corr[r] + ps;
    }
    #pragma unroll
    for (int dg = 0; dg < 4; ++dg)
      #pragma unroll
      for (int r = 0; r < 4; ++r) accO[dg][r] *= corr[r];
    // O += P V  (P from per-wave LDS; V direct from global)
    #pragma unroll
    for (int ks = 0; ks < 2; ++ks) {
      short8 pa = *reinterpret_cast<const short8*>(&Pl[w][c][ks*32 + hi*8]);
      short8 vb0, vb1, vb2, vb3;
      #pragma unroll
      for (int i = 0; i < 8; ++i) {
        int key = kt + ks*32 + hi*8 + i; if (key > Lk-1) key = Lk-1;
        const unsigned short* vp = Vp + ((size_t)key*BATCH + b)*DD + hb + c;
        vb0[i] = (short)vp[0];
        vb1[i] = (short)vp[16];
        vb2[i] = (short)vp[32];
        vb3[i] = (short)vp[48];
      }
      accO[0] = __builtin_amdgcn_mfma_f32_16x16x32_bf16(pa, vb0, accO[0], 0, 0, 0);
      accO[1] = __builtin_amdgcn_mfma_f32_16x16x32_bf16(pa, vb1, accO[1], 0, 0, 0);
      accO[2] = __builtin_amdgcn_mfma_f32_16x16x32_bf16(pa, vb2, accO[2], 0, 0, 0);
      accO[3] = __builtin_amdgcn_mfma_f32_16x16x32_bf16(pa, vb3, accO[3], 0, 0, 0);
    }
    __syncthreads();
  }
  #pragma unroll
  for (int r = 0; r < 4; ++r) {
    int qg = qbase + r;
    if (qg < Lq) {
      float inv = 1.f / l_[r];
      #pragma unroll
      for (int dg = 0; dg < 4; ++dg)
        Ob[((size_t)qg*BATCH + b)*DD + hb + 16*dg + c] = f2bf(accO[dg][r] * inv);
    }
  }
}

// ================= f32 GEMM (small MLPs, kept for accuracy) =================
__global__ __launch_bounds__(256) void gemm_f32(
    const float* __restrict__ A, const float* __restrict__ A2,
    const float* __restrict__ W, const float* __restrict__ bias,
    float* __restrict__ C, int M, int N, int K, int lda, int relu)
{
  __shared__ __align__(16) float As[16][68];
  __shared__ __align__(16) float Bs[16][68];
  const int tid = threadIdx.x;
  const int bm = blockIdx.y * 64, bn = blockIdx.x * 64;
  const int tx = tid & 15, ty = tid >> 4;
  const int ar = tid >> 4, ac = tid & 15;
  const int bk = tid >> 6, bnn = tid & 63;
  float acc[4][4] = {};
  for (int k0 = 0; k0 < K; k0 += 16) {
    #pragma unroll
    for (int i = 0; i < 4; ++i) {
      int row = ar + i*16;
      float v = A[(size_t)(bm+row)*lda + (k0+ac)];
      if (A2) v += A2[(size_t)(bm+row)*lda + (k0+ac)];
      As[ac][row] = v;
    }
    #pragma unroll
    for (int i = 0; i < 4; ++i) {
      int kk = bk + i*4;
      Bs[kk][bnn] = W[(size_t)(k0+kk)*N + (bn+bnn)];
    }
    __syncthreads();
    #pragma unroll
    for (int k = 0; k < 16; ++k) {
      float4 a4 = *reinterpret_cast<const float4*>(&As[k][ty*4]);
      float4 b4 = *reinterpret_cast<const float4*>(&Bs[k][tx*4]);
      float a[4] = {a4.x,a4.y,a4.z,a4.w};
      float bb[4] = {b4.x,b4.y,b4.z,b4.w};
      #pragma unroll
      for (int i=0;i<4;++i)
        #pragma unroll
        for (int j=0;j<4;++j)
          acc[i][j] = fmaf(a[i], bb[j], acc[i][j]);
    }
    __syncthreads();
  }
  float vb[4] = {0.f,0.f,0.f,0.f};
  if (bias) {
    float4 b4 = *reinterpret_cast<const float4*>(&bias[bn + tx*4]);
    vb[0]=b4.x; vb[1]=b4.y; vb[2]=b4.z; vb[3]=b4.w;
  }
  #pragma unroll
  for (int i=0;i<4;++i) {
    int row = bm + ty*4 + i;
    float r0 = acc[i][0]+vb[0], r1 = acc[i][1]+vb[1], r2 = acc[i][2]+vb[2], r3 = acc[i][3]+vb[3];
    if (relu){ r0=fmaxf(r0,0.f); r1=fmaxf(r1,0.f); r2=fmaxf(r2,0.f); r3=fmaxf(r3,0.f); }
    float4 o; o.x=r0; o.y=r1; o.z=r2; o.w=r3;
    *reinterpret_cast<float4*>(&C[(size_t)row*N + bn + tx*4]) = o;
  }
}

__global__ __launch_bounds__(256) void gemm_skinny(
    const float* __restrict__ A, const float* __restrict__ W, const float* __restrict__ bias,
    float* __restrict__ C, int M, int N, int K, int lda)
{
  int wid = threadIdx.x >> 6, lane = threadIdx.x & 63;
  int row = blockIdx.x * 4 + wid;
  if (row >= M) return;
  float acc[4] = {0.f,0.f,0.f,0.f};
  for (int k = lane; k < K; k += 64) {
    float av = A[(size_t)row*lda + k];
    for (int n = 0; n < N; ++n) acc[n] += av * W[(size_t)k*N + n];
  }
  for (int off = 32; off; off >>= 1)
    for (int n = 0; n < N; ++n) acc[n] += __shfl_down(acc[n], off);
  if (lane == 0)
    for (int n = 0; n < N; ++n) C[(size_t)row*N + n] = acc[n] + bias[n];
}

__global__ void sine_embed_kernel(const float* __restrict__ refb, float* __restrict__ sine)
{
  int idx = blockIdx.x*blockDim.x + threadIdx.x;
  if (idx >= NQROWS*DM) return;
  int r = idx >> 8, c = idx & 255;
  int j = c & 127;
  float coord = refb[r*2 + (c < 128 ? 1 : 0)];
  float s = sigmoidf_(coord);
  float freq = expf(-(float)(j >> 1) * (9.210340371976184f / 64.f));
  float v = s * 6.283185307179586f * freq;
  sine[idx] = (j & 1) ? cosf(v) : sinf(v);
}

__global__ void boxes_kernel(const float* __restrict__ t4, const float* __restrict__ refb,
                             float* __restrict__ boxes, float* __restrict__ cs)
{
  int idx = blockIdx.x*blockDim.x + threadIdx.x;
  if (idx >= NQROWS) return;
  int q = idx / BATCH, b = idx % BATCH;
  float cx = sigmoidf_(t4[idx*4+0] + refb[idx*2+0]);
  float cy = sigmoidf_(t4[idx*4+1] + refb[idx*2+1]);
  float w  = sigmoidf_(t4[idx*4+2]);
  float h  = sigmoidf_(t4[idx*4+3]);
  int o = b*QLEN + q;
  boxes[o*4+0] = cx - 0.5f*w;
  boxes[o*4+1] = cy - 0.5f*h;
  boxes[o*4+2] = cx + 0.5f*w;
  boxes[o*4+3] = cy + 0.5f*h;
  cs[o] = cx + cy;
}

__global__ void bias_kernel(const float* __restrict__ boxes, const float* __restrict__ cs,
                            float* __restrict__ bias)
{
  int idx = blockIdx.x*blockDim.x + threadIdx.x;
  const int QQ = QLEN*QLEN;
  if (idx >= BATCH*QQ) return;
  int b = idx / QQ, rem = idx - b*QQ;
  int i = rem / QLEN, j = rem - i*QLEN;
  float4 bi = *reinterpret_cast<const float4*>(&boxes[((size_t)b*QLEN + i)*4]);
  float4 bj = *reinterpret_cast<const float4*>(&boxes[((size_t)b*QLEN + j)*4]);
  float ai = (bi.z-bi.x)*(bi.w-bi.y);
  float aj = (bj.z-bj.x)*(bj.w-bj.y);
  float ltx = fmaxf(bi.x, bj.x), lty = fmaxf(bi.y, bj.y);
  float rbx = fminf(bi.z, bj.z), rby = fminf(bi.w, bj.w);
  float w = fmaxf(rbx-ltx, 0.f), h = fmaxf(rby-lty, 0.f);
  float inter = w*h;
  float iou = inter / (ai + aj - inter);
  bias[idx] = iou + ((cs[b*QLEN+i] > cs[b*QLEN+j]) ? 1.f : 0.f);
}

// QIN = bf16(X + qp2)
__global__ void add_qp2(const float* __restrict__ X, const float* __restrict__ qp,
                        unsigned short* __restrict__ out)
{
  int idx = blockIdx.x*blockDim.x + threadIdx.x;
  if (idx >= NQROWS*DD) return;
  int r = idx >> 9, c = idx & 511;
  out[idx] = f2bf(X[idx] + qp[(r<<8) + (c & 255)]);
}

// QIN = bf16(X + qp2 + (sine*pt)2)
__global__ void caq_kernel(const float* __restrict__ X, const float* __restrict__ qp,
                           const float* __restrict__ sine, const float* __restrict__ pt,
                           unsigned short* __restrict__ out)
{
  int idx = blockIdx.x*blockDim.x + threadIdx.x;
  if (idx >= NQROWS*DD) return;
  int r = idx >> 9, c = idx & 511;
  int c2 = (r<<8) + (c & 255);
  out[idx] = f2bf(X[idx] + qp[c2] + sine[c2]*pt[c2]);
}

// residual + LN, in-place on X, also emits bf16 copy
__global__ __launch_bounds__(256) void ln_residual(float* __restrict__ X, const float* __restrict__ Y,
                                                   unsigned short* __restrict__ Xb)
{
  int row = blockIdx.x, tid = threadIdx.x;
  size_t base = (size_t)row*DD;
  float v0 = X[base+tid]     + Y[base+tid];
  float v1 = X[base+tid+256] + Y[base+tid+256];
  float s = v0+v1, sq = v0*v0+v1*v1;
  for (int off = 32; off; off >>= 1) { s += __shfl_down(s,off); sq += __shfl_down(sq,off); }
  __shared__ float ss[4], ssq[4];
  int wid = tid>>6, lane = tid&63;
  if (lane==0){ ss[wid]=s; ssq[wid]=sq; }
  __syncthreads();
  if (tid==0){
    float a=ss[0]+ss[1]+ss[2]+ss[3], bsum=ssq[0]+ssq[1]+ssq[2]+ssq[3];
    float mean = a*(1.f/DD);
    float var  = bsum*(1.f/DD) - mean*mean;
    ss[0]=mean; ssq[0]=rsqrtf(fmaxf(var,0.f)+1e-5f);
  }
  __syncthreads();
  float mean = ss[0], inv = ssq[0];
  float o0 = (v0-mean)*inv, o1 = (v1-mean)*inv;
  X[base+tid]     = o0;  Xb[base+tid]     = f2bf(o0);
  X[base+tid+256] = o1;  Xb[base+tid+256] = f2bf(o1);
}

__global__ void init_x(const float* __restrict__ t, float* __restrict__ X,
                       unsigned short* __restrict__ Xb, int n)
{
  int idx = blockIdx.x*blockDim.x + threadIdx.x;
  if (idx < n){ float v = t[idx]; X[idx]=v; Xb[idx]=f2bf(v); }
}

__global__ void copy_f32(const float* __restrict__ src, float* __restrict__ dst, int n)
{
  int idx = blockIdx.x*blockDim.x + threadIdx.x;
  if (idx < n) dst[idx] = src[idx];
}

extern "C" void kernel_launch(void* const* d_in, const int* in_sizes, int n_in,
                              void* d_out, int out_size, void* d_ws, size_t ws_size,
                              hipStream_t stream)
{
  const float* tgt       = (const float*)d_in[0];
  const float* memory    = (const float*)d_in[1];
  const float* pos       = (const float*)d_in[2];
  const float* query_pos = (const float*)d_in[3];
  const float* qs_W1 = (const float*)d_in[4];  const float* qs_b1 = (const float*)d_in[5];
  const float* qs_W2 = (const float*)d_in[6];  const float* qs_b2 = (const float*)d_in[7];
  const float* rp_W1 = (const float*)d_in[8];  const float* rp_b1 = (const float*)d_in[9];
  const float* rp_W2 = (const float*)d_in[10]; const float* rp_b2 = (const float*)d_in[11];
  const float* bb_W1 = (const float*)d_in[12]; const float* bb_b1 = (const float*)d_in[13];
  const float* bb_W2 = (const float*)d_in[14]; const float* bb_b2 = (const float*)d_in[15];
  const float* sa_Wq = (const float*)d_in[16]; const float* sa_Wk = (const float*)d_in[17];
  const float* sa_Wv = (const float*)d_in[18]; const float* sa_Wo = (const float*)d_in[19];
  const float* ca_Wq = (const float*)d_in[20]; const float* ca_Wk = (const float*)d_in[21];
  const float* ca_Wv = (const float*)d_in[22]; const float* ca_Wo = (const float*)d_in[23];
  const float* ff_W1 = (const float*)d_in[24]; const float* ff_b1 = (const float*)d_in[25];
  const float* ff_W2 = (const float*)d_in[26]; const float* ff_b2 = (const float*)d_in[27];

  // ---------- workspace layout ----------
  float* F = (float*)d_ws;
  size_t o = 0;
  float* X    = F + o; o += (size_t)NQROWS*DD;        // residual stream f32
  float* RES  = F + o; o += (size_t)NQROWS*DD;        // Wo/FFN2 output; first half doubles as T256
  float* SINE = F + o; o += (size_t)NQROWS*DM;
  float* PT   = F + o; o += (size_t)NQROWS*DM;
  float* BIAS = F + o; o += (size_t)BATCH*QLEN*QLEN;
  float* REFB = F + o; o += (size_t)NQROWS*2;
  float* T4   = F + o; o += (size_t)NQROWS*4;
  float* BOX  = F + o; o += (size_t)NQROWS*4;
  float* CS   = F + o; o += (size_t)NQROWS;
  float* T256 = RES;                                   // alias (lifetime-disjoint)
  unsigned short* U = (unsigned short*)(F + o);
  size_t u = 0;
  unsigned short* Xb   = U + u; u += (size_t)NQROWS*DD;
  unsigned short* QIN  = U + u; u += (size_t)NQROWS*DD;   // also attention output
  unsigned short* PQb  = U + u; u += (size_t)NQROWS*DD;
  unsigned short* PKb  = U + u; u += (size_t)NMROWS*DD;   // also FFN hidden
  unsigned short* PVb  = U + u; u += (size_t)NMROWS*DD;
  unsigned short* WtSq = U + u; u += (size_t)6*DD*DD;
  unsigned short* WtSk = U + u; u += (size_t)6*DD*DD;
  unsigned short* WtSv = U + u; u += (size_t)6*DD*DD;
  unsigned short* WtSo = U + u; u += (size_t)6*DD*DD;
  unsigned short* WtCq = U + u; u += (size_t)6*DD*DD;
  unsigned short* WtCk = U + u; u += (size_t)6*DD*DD;
  unsigned short* WtCv = U + u; u += (size_t)6*DD*DD;
  unsigned short* WtCo = U + u; u += (size_t)6*DD*DD;
  unsigned short* WtF1 = U + u; u += (size_t)6*DD*FFND;
  unsigned short* WtF2 = U + u; u += (size_t)6*DD*FFND;
  unsigned short* AOb  = QIN;
  unsigned short* HIDb = PKb;
  if (ws_size < o*sizeof(float) + u*sizeof(unsigned short)) return;

  dim3 B256(256);
  const int nTotal = NQROWS*DD;

  // ---------- weight transpose+cvt (once per call) ----------
  transpose_cvt<<<dim3(16,16,6), B256, 0, stream>>>(sa_Wq, WtSq, DD, DD);
  transpose_cvt<<<dim3(16,16,6), B256, 0, stream>>>(sa_Wk, WtSk, DD, DD);
  transpose_cvt<<<dim3(16,16,6), B256, 0, stream>>>(sa_Wv, WtSv, DD, DD);
  transpose_cvt<<<dim3(16,16,6), B256, 0, stream>>>(sa_Wo, WtSo, DD, DD);
  transpose_cvt<<<dim3(16,16,6), B256, 0, stream>>>(ca_Wq, WtCq, DD, DD);
  transpose_cvt<<<dim3(16,16,6), B256, 0, stream>>>(ca_Wk, WtCk, DD, DD);
  transpose_cvt<<<dim3(16,16,6), B256, 0, stream>>>(ca_Wv, WtCv, DD, DD);
  transpose_cvt<<<dim3(16,16,6), B256, 0, stream>>>(ca_Wo, WtCo, DD, DD);
  transpose_cvt<<<dim3(32,16,6), B256, 0, stream>>>(ff_W1, WtF1, DD, FFND);
  transpose_cvt<<<dim3(16,32,6), B256, 0, stream>>>(ff_W2, WtF2, FFND, DD);

  // ---------- pre-loop ----------
  init_x<<<dim3((nTotal+255)/256), B256, 0, stream>>>(tgt, X, Xb, nTotal);
  gemm_f32<<<dim3(DM/64, NQROWS/64), B256, 0, stream>>>(query_pos, nullptr, rp_W1, rp_b1, T256, NQROWS, DM, DM, DM, 1);
  gemm_skinny<<<dim3(NQROWS/4), B256, 0, stream>>>(T256, rp_W2, rp_b2, REFB, NQROWS, 2, DM, DM);
  sine_embed_kernel<<<dim3((NQROWS*DM+255)/256), B256, 0, stream>>>(REFB, SINE);

  for (int l = 0; l < 6; ++l) {
    const size_t wo = (size_t)l*DD*DD, fo = (size_t)l*DD*FFND;
    const float* fb1 = ff_b1 + (size_t)l*FFND;
    const float* fb2 = ff_b2 + (size_t)l*DD;

    // pos_transform MLP (f32, accuracy-sensitive downstream path shares X)
    gemm_f32<<<dim3(DM/64, NQROWS/64), B256, 0, stream>>>(X+DM, nullptr, qs_W1, qs_b1, T256, NQROWS, DM, DM, DD, 1);
    gemm_f32<<<dim3(DM/64, NQROWS/64), B256, 0, stream>>>(T256, nullptr, qs_W2, qs_b2, PT,  NQROWS, DM, DM, DM, 0);
    // bbox MLP -> boxes -> bias (f32: comparison cs_i>cs_j is flip-sensitive)
    gemm_f32<<<dim3(DM/64, NQROWS/64), B256, 0, stream>>>(X+DM, nullptr, bb_W1, bb_b1, T256, NQROWS, DM, DM, DD, 1);
    gemm_skinny<<<dim3(NQROWS/4), B256, 0, stream>>>(T256, bb_W2, bb_b2, T4, NQROWS, 4, DM, DM);
    boxes_kernel<<<dim3((NQROWS+255)/256), B256, 0, stream>>>(T4, REFB, BOX, CS);
    bias_kernel<<<dim3((BATCH*QLEN*QLEN+255)/256), B256, 0, stream>>>(BOX, CS, BIAS);

    // ---- self-attention ----
    add_qp2<<<dim3((nTotal+255)/256), B256, 0, stream>>>(X, query_pos, QIN);
    gemm_mfma<0,true,false><<<dim3(DD/64, NQROWS/64), B256, 0, stream>>>(QIN, nullptr, WtSq+wo, nullptr, PQb, NQROWS, DD, DD, DD);
    gemm_mfma<0,true,false><<<dim3(DD/64, NQROWS/64), B256, 0, stream>>>(QIN, nullptr, WtSk+wo, nullptr, PKb, NQROWS, DD, DD, DD);
    gemm_mfma<0,true,false><<<dim3(DD/64, NQROWS/64), B256, 0, stream>>>(Xb,  nullptr, WtSv+wo, nullptr, PVb, NQROWS, DD, DD, DD);
    attn_mfma<true><<<dim3((QLEN+63)/64, BATCH*8), B256, 0, stream>>>(PQb, PKb, PVb, BIAS, AOb, QLEN, QLEN);
    gemm_mfma<0,false,false><<<dim3(DD/64, NQROWS/64), B256, 0, stream>>>(AOb, nullptr, WtSo+wo, nullptr, RES, NQROWS, DD, DD, DD);
    ln_residual<<<dim3(NQROWS), B256, 0, stream>>>(X, RES, Xb);

    // ---- cross-attention ----
    caq_kernel<<<dim3((nTotal+255)/256), B256, 0, stream>>>(X, query_pos, SINE, PT, QIN);
    gemm_mfma<0,true,false><<<dim3(DD/64, NQROWS/64), B256, 0, stream>>>(QIN, nullptr, WtCq+wo, nullptr, PQb, NQROWS, DD, DD, DD);
    gemm_mfma<2,true,false><<<dim3(DD/64, NMROWS/64), B256, 0, stream>>>(memory, pos, WtCk+wo, nullptr, PKb, NMROWS, DD, DD, DD);
    gemm_mfma<1,true,false><<<dim3(DD/64, NMROWS/64), B256, 0, stream>>>(memory, nullptr, WtCv+wo, nullptr, PVb, NMROWS, DD, DD, DD);
    attn_mfma<false><<<dim3((QLEN+63)/64, BATCH*8), B256, 0, stream>>>(PQb, PKb, PVb, nullptr, AOb, QLEN, SLEN);
    gemm_mfma<0,false,false><<<dim3(DD/64, NQROWS/64), B256, 0, stream>>>(AOb, nullptr, WtCo+wo, nullptr, RES, NQROWS, DD, DD, DD);
    ln_residual<<<dim3(NQROWS), B256, 0, stream>>>(X, RES, Xb);

    // ---- FFN ----
    gemm_mfma<0,true,true ><<<dim3(FFND/64, NQROWS/64), B256, 0, stream>>>(Xb, nullptr, WtF1+fo, fb1, HIDb, NQROWS, FFND, DD, DD);
    gemm_mfma<0,false,false><<<dim3(DD/64, NQROWS/64), B256, 0, stream>>>(HIDb, nullptr, WtF2+fo, fb2, RES, NQROWS, DD, FFND, FFND);
    ln_residual<<<dim3(NQROWS), B256, 0, stream>>>(X, RES, Xb);
  }

  copy_f32<<<dim3((nTotal+255)/256), B256, 0, stream>>>(X, (float*)d_out, out_size);
}

// Round 3
// 2233.942 us; speedup vs baseline: 4.5654x; 1.3659x over previous
//
#include <hip/hip_runtime.h>
#include <cmath>

#define QLEN 300
#define BATCH 16
#define SLEN 1024
#define DM 256
#define DD 512
#define FFND 1024
#define NQROWS (QLEN*BATCH)   // 4800
#define NMROWS (SLEN*BATCH)   // 16384

typedef __attribute__((ext_vector_type(8))) short short8;
typedef __attribute__((ext_vector_type(4))) float f32x4;

__device__ __forceinline__ float sigmoidf_(float x){ return 1.f/(1.f+expf(-x)); }

__device__ __forceinline__ unsigned short f2bf(float x){
  unsigned u = __float_as_uint(x);
  unsigned r = (u + 0x7FFFu + ((u >> 16) & 1u)) >> 16;
  return (unsigned short)r;
}

// async global->LDS, 16B per lane; dest = wave-uniform base + lane*16
__device__ __forceinline__ void gload16(const void* g, void* l) {
  __builtin_amdgcn_global_load_lds((const __attribute__((address_space(1))) unsigned int*)g,
                                   (__attribute__((address_space(3))) unsigned int*)l, 16, 0, 0);
}

// ================= weight transpose + f32->bf16 : W[K,N] -> Wt[N,K] =================
__global__ __launch_bounds__(256) void transpose_cvt(
    const float* __restrict__ W, unsigned short* __restrict__ Wt, int K, int N)
{
  __shared__ float T[32][33];
  int n0 = blockIdx.x*32, k0 = blockIdx.y*32;
  size_t zo = (size_t)blockIdx.z * K * N;
  int tx = threadIdx.x & 31, ty = threadIdx.x >> 5;
  #pragma unroll
  for (int j = 0; j < 32; j += 8)
    T[ty+j][tx] = W[zo + (size_t)(k0+ty+j)*N + n0+tx];
  __syncthreads();
  #pragma unroll
  for (int j = 0; j < 32; j += 8)
    Wt[zo + (size_t)(n0+ty+j)*K + k0+tx] = f2bf(T[tx][ty+j]);
}

// ================= gemm2: m97-style bf16 MFMA GEMM, BN=128, BK=64 =================
// C[M,N] = act(A @ Wt^T + bias). Wt bf16 [N,K]. M % BM == 0, N % 128 == 0, K % 64 == 0.
// AMODE 0: A bf16 (gload_lds); 1: A f32; 2: f32 A+A2 (reg-staged cvt).
// LDS layout linear [rows][64] ushort, element (r,kk) at col kk ^ ((r&7)<<3) (ushort idx).
template<int BM, int AMODE, bool OUTBF16, bool RELU>
__global__ __launch_bounds__(256) void gemm2(
    const void* __restrict__ Aptr, const float* __restrict__ A2,
    const unsigned short* __restrict__ Wt, const float* __restrict__ bias,
    void* __restrict__ Cptr, int M, int N, int K, int lda)
{
  __shared__ __align__(16) unsigned short As[BM*64];
  __shared__ __align__(16) unsigned short Bs[128*64];
  const int tid = threadIdx.x;
  const int w = tid >> 6, lane = tid & 63;
  const int bm = blockIdx.y*BM, bn = blockIdx.x*128;
  const int wm = w >> 1, wn = w & 1;
  const int c = lane & 15, hi = lane >> 4;
  constexpr int MR = BM/32;
  f32x4 acc[MR][4] = {};
  const int lrow8 = lane >> 3;                    // 0..7
  const int lcol  = ((lane & 7) ^ lrow8) << 3;    // pre-swizzled ushort col

  for (int k0 = 0; k0 < K; k0 += 64) {
    if (AMODE == 0) {
      const unsigned short* Ab = (const unsigned short*)Aptr;
      #pragma unroll
      for (int it = 0; it < BM/32; ++it) {
        int r = it*32 + w*8;
        gload16(&Ab[(size_t)(bm + r + lrow8)*lda + k0 + lcol], &As[r*64]);
      }
    } else {
      const float* Af = (const float*)Aptr;
      #pragma unroll
      for (int it = 0; it < BM/32; ++it) {
        int r = it*32 + (tid>>3);
        size_t base = (size_t)(bm + r)*lda + k0 + (tid&7)*8;
        float4 f0 = *reinterpret_cast<const float4*>(&Af[base]);
        float4 f1 = *reinterpret_cast<const float4*>(&Af[base+4]);
        if (AMODE == 2) {
          float4 g0 = *reinterpret_cast<const float4*>(&A2[base]);
          float4 g1 = *reinterpret_cast<const float4*>(&A2[base+4]);
          f0.x+=g0.x; f0.y+=g0.y; f0.z+=g0.z; f0.w+=g0.w;
          f1.x+=g1.x; f1.y+=g1.y; f1.z+=g1.z; f1.w+=g1.w;
        }
        short8 v;
        v[0]=(short)f2bf(f0.x); v[1]=(short)f2bf(f0.y); v[2]=(short)f2bf(f0.z); v[3]=(short)f2bf(f0.w);
        v[4]=(short)f2bf(f1.x); v[5]=(short)f2bf(f1.y); v[6]=(short)f2bf(f1.z); v[7]=(short)f2bf(f1.w);
        *reinterpret_cast<short8*>(&As[r*64 + (((tid&7)*8) ^ ((r&7)<<3))]) = v;
      }
    }
    #pragma unroll
    for (int it = 0; it < 4; ++it) {
      int r = it*32 + w*8;
      gload16(&Wt[(size_t)(bn + r + lrow8)*K + k0 + lcol], &Bs[r*64]);
    }
    __syncthreads();
    #pragma unroll
    for (int ks = 0; ks < 2; ++ks) {
      short8 a[MR], bf[4];
      #pragma unroll
      for (int mr = 0; mr < MR; ++mr) {
        int m = wm*(BM/2) + mr*16 + c;
        a[mr] = *reinterpret_cast<const short8*>(&As[m*64 + ((ks*32 + hi*8) ^ ((m&7)<<3))]);
      }
      #pragma unroll
      for (int nr = 0; nr < 4; ++nr) {
        int n = wn*64 + nr*16 + c;
        bf[nr] = *reinterpret_cast<const short8*>(&Bs[n*64 + ((ks*32 + hi*8) ^ ((n&7)<<3))]);
      }
      #pragma unroll
      for (int mr = 0; mr < MR; ++mr)
        #pragma unroll
        for (int nr = 0; nr < 4; ++nr)
          acc[mr][nr] = __builtin_amdgcn_mfma_f32_16x16x32_bf16(a[mr], bf[nr], acc[mr][nr], 0, 0, 0);
    }
    __syncthreads();
  }
  #pragma unroll
  for (int mr = 0; mr < MR; ++mr) {
    #pragma unroll
    for (int nr = 0; nr < 4; ++nr) {
      int colg = bn + wn*64 + nr*16 + c;
      float bv = bias ? bias[colg] : 0.f;
      #pragma unroll
      for (int r = 0; r < 4; ++r) {
        int rowg = bm + wm*(BM/2) + mr*16 + hi*4 + r;
        float v = acc[mr][nr][r] + bv;
        if (RELU) v = fmaxf(v, 0.f);
        if (OUTBF16) ((unsigned short*)Cptr)[(size_t)rowg*N + colg] = f2bf(v);
        else         ((float*)Cptr)[(size_t)rowg*N + colg] = v;
      }
    }
  }
}

// ================= old 64x64 MFMA GEMM (N=256 paths) =================
template<int AMODE, bool OUTBF16, bool RELU>
__global__ __launch_bounds__(256) void gemm_mfma(
    const void* __restrict__ Aptr, const float* __restrict__ A2,
    const unsigned short* __restrict__ Wt, const float* __restrict__ bias,
    void* __restrict__ Cptr, int M, int N, int K, int lda)
{
  __shared__ __align__(16) unsigned short As[64][72];
  __shared__ __align__(16) unsigned short Bs[64][72];
  const int tid = threadIdx.x;
  const int bm = blockIdx.y*64, bn = blockIdx.x*64;
  const int w = tid >> 6, lane = tid & 63;
  const int wm = w >> 1, wn = w & 1;
  const int c = lane & 15, hi = lane >> 4;
  const int sr = tid >> 3, sk = (tid & 7) * 8;
  f32x4 acc[2][2] = {};
  for (int k0 = 0; k0 < K; k0 += 64) {
    #pragma unroll
    for (int it = 0; it < 2; ++it) {
      int m = sr + it*32;
      if (AMODE == 0) {
        const unsigned short* Ab = (const unsigned short*)Aptr;
        short8 v = *reinterpret_cast<const short8*>(&Ab[(size_t)(bm+m)*lda + k0 + sk]);
        *reinterpret_cast<short8*>(&As[m][sk]) = v;
      } else {
        const float* Af = (const float*)Aptr;
        size_t base = (size_t)(bm+m)*lda + k0 + sk;
        float4 f0 = *reinterpret_cast<const float4*>(&Af[base]);
        float4 f1 = *reinterpret_cast<const float4*>(&Af[base+4]);
        if (AMODE == 2) {
          float4 g0 = *reinterpret_cast<const float4*>(&A2[base]);
          float4 g1 = *reinterpret_cast<const float4*>(&A2[base+4]);
          f0.x+=g0.x; f0.y+=g0.y; f0.z+=g0.z; f0.w+=g0.w;
          f1.x+=g1.x; f1.y+=g1.y; f1.z+=g1.z; f1.w+=g1.w;
        }
        short8 v;
        v[0]=(short)f2bf(f0.x); v[1]=(short)f2bf(f0.y); v[2]=(short)f2bf(f0.z); v[3]=(short)f2bf(f0.w);
        v[4]=(short)f2bf(f1.x); v[5]=(short)f2bf(f1.y); v[6]=(short)f2bf(f1.z); v[7]=(short)f2bf(f1.w);
        *reinterpret_cast<short8*>(&As[m][sk]) = v;
      }
      short8 bv = *reinterpret_cast<const short8*>(&Wt[(size_t)(bn+m)*K + k0 + sk]);
      *reinterpret_cast<short8*>(&Bs[m][sk]) = bv;
    }
    __syncthreads();
    #pragma unroll
    for (int ks = 0; ks < 2; ++ks) {
      short8 a0 = *reinterpret_cast<const short8*>(&As[wm*32 + c][ks*32 + hi*8]);
      short8 a1 = *reinterpret_cast<const short8*>(&As[wm*32 + 16 + c][ks*32 + hi*8]);
      short8 b0 = *reinterpret_cast<const short8*>(&Bs[wn*32 + c][ks*32 + hi*8]);
      short8 b1 = *reinterpret_cast<const short8*>(&Bs[wn*32 + 16 + c][ks*32 + hi*8]);
      acc[0][0] = __builtin_amdgcn_mfma_f32_16x16x32_bf16(a0, b0, acc[0][0], 0, 0, 0);
      acc[0][1] = __builtin_amdgcn_mfma_f32_16x16x32_bf16(a0, b1, acc[0][1], 0, 0, 0);
      acc[1][0] = __builtin_amdgcn_mfma_f32_16x16x32_bf16(a1, b0, acc[1][0], 0, 0, 0);
      acc[1][1] = __builtin_amdgcn_mfma_f32_16x16x32_bf16(a1, b1, acc[1][1], 0, 0, 0);
    }
    __syncthreads();
  }
  #pragma unroll
  for (int mf = 0; mf < 2; ++mf) {
    #pragma unroll
    for (int nf = 0; nf < 2; ++nf) {
      int colg = bn + wn*32 + nf*16 + c;
      float bv = bias ? bias[colg] : 0.f;
      #pragma unroll
      for (int r = 0; r < 4; ++r) {
        int rowg = bm + wm*32 + mf*16 + hi*4 + r;
        float v = acc[mf][nf][r] + bv;
        if (RELU) v = fmaxf(v, 0.f);
        if (OUTBF16) ((unsigned short*)Cptr)[(size_t)rowg*N + colg] = f2bf(v);
        else         ((float*)Cptr)[(size_t)rowg*N + colg] = v;
      }
    }
  }
}

// ================= MFMA flash attention (K via gload_lds, V via LDS transpose) ======
// Qp/Kp/Vp bf16 [L*B,512] row = l*B+b; head h -> cols h*64..+63. bias f32 [B,Lq,Lk].
// grid: (ceil(Lq/64), B*8), block 256 (4 waves, 16 q-rows each).
template<bool HAS_BIAS>
__global__ __launch_bounds__(256) void attn_mfma(
    const unsigned short* __restrict__ Qp, const unsigned short* __restrict__ Kp,
    const unsigned short* __restrict__ Vp, const float* __restrict__ bias,
    unsigned short* __restrict__ Ob, int Lq, int Lk)
{
  __shared__ __align__(16) unsigned short Ks[64*64];     // swizzled like gemm2
  __shared__ __align__(16) unsigned short Vt[64][72];    // [d][rot-swizzled key]
  __shared__ __align__(16) unsigned short Pl[4][16][72]; // per-wave P
  const int tid = threadIdx.x;
  const int w = tid >> 6, lane = tid & 63;
  const int c = lane & 15, hi = lane >> 4;
  const int h = blockIdx.y & 7, b = blockIdx.y >> 3;
  const int qt = blockIdx.x * 64;
  const int hb = h * 64;
  const int lrow8 = lane >> 3;
  const int lcol  = ((lane & 7) ^ lrow8) << 3;

  int qrow = qt + w*16 + c; if (qrow > Lq-1) qrow = Lq-1;
  const unsigned short* qptr = Qp + ((size_t)qrow*BATCH + b)*DD + hb;
  short8 qf0 = *reinterpret_cast<const short8*>(qptr + hi*8);
  short8 qf1 = *reinterpret_cast<const short8*>(qptr + 32 + hi*8);

  float m_[4], l_[4];
  f32x4 accO[4] = {};
  #pragma unroll
  for (int r = 0; r < 4; ++r) { m_[r] = -1e30f; l_[r] = 0.f; }

  const int qbase = qt + w*16 + hi*4;
  const int nt = (Lk + 63) >> 6;
  for (int t = 0; t < nt; ++t) {
    const int kt = t * 64;
    // ---- stage K (async direct-to-LDS, pre-swizzled source) ----
    #pragma unroll
    for (int it = 0; it < 2; ++it) {
      int kr = kt + it*32 + w*8 + lrow8; if (kr > Lk-1) kr = Lk-1;
      gload16(&Kp[((size_t)kr*BATCH + b)*DD + hb + lcol], &Ks[(it*32 + w*8)*64]);
    }
    // ---- stage V transposed, rotation swizzle key' = (key + 8*((d>>3)&7)) & 63 ----
    #pragma unroll
    for (int it = 0; it < 2; ++it) {
      int keyl = it*32 + (tid>>3);
      int vr = kt + keyl; if (vr > Lk-1) vr = Lk-1;
      short8 v = *reinterpret_cast<const short8*>(&Vp[((size_t)vr*BATCH + b)*DD + hb + (tid&7)*8]);
      int key2 = (keyl + ((tid&7)<<3)) & 63;
      #pragma unroll
      for (int j = 0; j < 8; ++j)
        Vt[(tid&7)*8 + j][key2] = (unsigned short)v[j];
    }
    __syncthreads();
    // ---- S = Q K^T ----
    f32x4 s[4] = {};
    #pragma unroll
    for (int g = 0; g < 4; ++g) {
      int m = g*16 + c;
      short8 kb0 = *reinterpret_cast<const short8*>(&Ks[m*64 + ((hi*8) ^ ((c&7)<<3))]);
      short8 kb1 = *reinterpret_cast<const short8*>(&Ks[m*64 + ((32 + hi*8) ^ ((c&7)<<3))]);
      s[g] = __builtin_amdgcn_mfma_f32_16x16x32_bf16(qf0, kb0, s[g], 0, 0, 0);
      s[g] = __builtin_amdgcn_mfma_f32_16x16x32_bf16(qf1, kb1, s[g], 0, 0, 0);
    }
    // ---- logits + online softmax; lane holds S[q=hi*4+r][key=c+16g] ----
    float p[4][4];
    float tmax[4] = {-1e30f, -1e30f, -1e30f, -1e30f};
    #pragma unroll
    for (int g = 0; g < 4; ++g) {
      int kg = kt + g*16 + c;
      bool kvalid = kg < Lk;
      int kgc = kvalid ? kg : Lk-1;
      #pragma unroll
      for (int r = 0; r < 4; ++r) {
        float v = s[g][r] * 0.125f;
        if (HAS_BIAS) {
          int qg = qbase + r; if (qg > Lq-1) qg = Lq-1;
          v += bias[((size_t)b*Lq + qg)*Lk + kgc];
        }
        if (!kvalid) v = -1e30f;
        p[g][r] = v;
        tmax[r] = fmaxf(tmax[r], v);
      }
    }
    float corr[4], newm[4];
    #pragma unroll
    for (int r = 0; r < 4; ++r) {
      float tm = tmax[r];
      tm = fmaxf(tm, __shfl_xor(tm, 1));
      tm = fmaxf(tm, __shfl_xor(tm, 2));
      tm = fmaxf(tm, __shfl_xor(tm, 4));
      tm = fmaxf(tm, __shfl_xor(tm, 8));
      newm[r] = fmaxf(m_[r], tm);
      corr[r] = expf(m_[r] - newm[r]);
      m_[r] = newm[r];
    }
    float psum[4] = {0.f, 0.f, 0.f, 0.f};
    #pragma unroll
    for (int g = 0; g < 4; ++g)
      #pragma unroll
      for (int r = 0; r < 4; ++r) {
        float e = expf(p[g][r] - newm[r]);
        psum[r] += e;
        Pl[w][hi*4 + r][c + 16*g] = f2bf(e);
      }
    #pragma unroll
    for (int r = 0; r < 4; ++r) {
      float ps = psum[r];
      ps += __shfl_xor(ps, 1);
      ps += __shfl_xor(ps, 2);
      ps += __shfl_xor(ps, 4);
      ps += __shfl_xor(ps, 8);
      l_[r] = l_[r]*corr[r] + ps;
    }
    #pragma unroll
    for (int dg = 0; dg < 4; ++dg)
      #pragma unroll
      for (int r = 0; r < 4; ++r) accO[dg][r] *= corr[r];
    // ---- O += P V (P per-wave LDS, V from transposed LDS, all b128) ----
    #pragma unroll
    for (int ks = 0; ks < 2; ++ks) {
      short8 pa = *reinterpret_cast<const short8*>(&Pl[w][c][ks*32 + hi*8]);
      #pragma unroll
      for (int dg = 0; dg < 4; ++dg) {
        int d = c + 16*dg;
        int key2 = ((ks*32 + hi*8) + (((c>>3) + 2*dg) << 3)) & 63;
        short8 vb = *reinterpret_cast<const short8*>(&Vt[d][key2]);
        accO[dg] = __builtin_amdgcn_mfma_f32_16x16x32_bf16(pa, vb, accO[dg], 0, 0, 0);
      }
    }
    __syncthreads();
  }
  #pragma unroll
  for (int r = 0; r < 4; ++r) {
    int qg = qbase + r;
    if (qg < Lq) {
      float inv = 1.f / l_[r];
      #pragma unroll
      for (int dg = 0; dg < 4; ++dg)
        Ob[((size_t)qg*BATCH + b)*DD + hb + 16*dg + c] = f2bf(accO[dg][r] * inv);
    }
  }
}

// ================= f32 GEMM (bbox path, accuracy-sensitive) =================
__global__ __launch_bounds__(256) void gemm_f32(
    const float* __restrict__ A, const float* __restrict__ A2,
    const float* __restrict__ W, const float* __restrict__ bias,
    float* __restrict__ C, int M, int N, int K, int lda, int relu)
{
  __shared__ __align__(16) float As[16][68];
  __shared__ __align__(16) float Bs[16][68];
  const int tid = threadIdx.x;
  const int bm = blockIdx.y * 64, bn = blockIdx.x * 64;
  const int tx = tid & 15, ty = tid >> 4;
  const int ar = tid >> 4, ac = tid & 15;
  const int bk = tid >> 6, bnn = tid & 63;
  float acc[4][4] = {};
  for (int k0 = 0; k0 < K; k0 += 16) {
    #pragma unroll
    for (int i = 0; i < 4; ++i) {
      int row = ar + i*16;
      float v = A[(size_t)(bm+row)*lda + (k0+ac)];
      if (A2) v += A2[(size_t)(bm+row)*lda + (k0+ac)];
      As[ac][row] = v;
    }
    #pragma unroll
    for (int i = 0; i < 4; ++i) {
      int kk = bk + i*4;
      Bs[kk][bnn] = W[(size_t)(k0+kk)*N + (bn+bnn)];
    }
    __syncthreads();
    #pragma unroll
    for (int k = 0; k < 16; ++k) {
      float4 a4 = *reinterpret_cast<const float4*>(&As[k][ty*4]);
      float4 b4 = *reinterpret_cast<const float4*>(&Bs[k][tx*4]);
      float a[4] = {a4.x,a4.y,a4.z,a4.w};
      float bb[4] = {b4.x,b4.y,b4.z,b4.w};
      #pragma unroll
      for (int i=0;i<4;++i)
        #pragma unroll
        for (int j=0;j<4;++j)
          acc[i][j] = fmaf(a[i], bb[j], acc[i][j]);
    }
    __syncthreads();
  }
  float vb[4] = {0.f,0.f,0.f,0.f};
  if (bias) {
    float4 b4 = *reinterpret_cast<const float4*>(&bias[bn + tx*4]);
    vb[0]=b4.x; vb[1]=b4.y; vb[2]=b4.z; vb[3]=b4.w;
  }
  #pragma unroll
  for (int i=0;i<4;++i) {
    int row = bm + ty*4 + i;
    float r0 = acc[i][0]+vb[0], r1 = acc[i][1]+vb[1], r2 = acc[i][2]+vb[2], r3 = acc[i][3]+vb[3];
    if (relu){ r0=fmaxf(r0,0.f); r1=fmaxf(r1,0.f); r2=fmaxf(r2,0.f); r3=fmaxf(r3,0.f); }
    float4 o; o.x=r0; o.y=r1; o.z=r2; o.w=r3;
    *reinterpret_cast<float4*>(&C[(size_t)row*N + bn + tx*4]) = o;
  }
}

__global__ __launch_bounds__(256) void gemm_skinny(
    const float* __restrict__ A, const float* __restrict__ W, const float* __restrict__ bias,
    float* __restrict__ C, int M, int N, int K, int lda)
{
  int wid = threadIdx.x >> 6, lane = threadIdx.x & 63;
  int row = blockIdx.x * 4 + wid;
  if (row >= M) return;
  float acc[4] = {0.f,0.f,0.f,0.f};
  for (int k = lane; k < K; k += 64) {
    float av = A[(size_t)row*lda + k];
    for (int n = 0; n < N; ++n) acc[n] += av * W[(size_t)k*N + n];
  }
  for (int off = 32; off; off >>= 1)
    for (int n = 0; n < N; ++n) acc[n] += __shfl_down(acc[n], off);
  if (lane == 0)
    for (int n = 0; n < N; ++n) C[(size_t)row*N + n] = acc[n] + bias[n];
}

__global__ void sine_embed_kernel(const float* __restrict__ refb, float* __restrict__ sine)
{
  int idx = blockIdx.x*blockDim.x + threadIdx.x;
  if (idx >= NQROWS*DM) return;
  int r = idx >> 8, c = idx & 255;
  int j = c & 127;
  float coord = refb[r*2 + (c < 128 ? 1 : 0)];
  float s = sigmoidf_(coord);
  float freq = expf(-(float)(j >> 1) * (9.210340371976184f / 64.f));
  float v = s * 6.283185307179586f * freq;
  sine[idx] = (j & 1) ? cosf(v) : sinf(v);
}

__global__ void boxes_kernel(const float* __restrict__ t4, const float* __restrict__ refb,
                             float* __restrict__ boxes, float* __restrict__ cs)
{
  int idx = blockIdx.x*blockDim.x + threadIdx.x;
  if (idx >= NQROWS) return;
  int q = idx / BATCH, b = idx % BATCH;
  float cx = sigmoidf_(t4[idx*4+0] + refb[idx*2+0]);
  float cy = sigmoidf_(t4[idx*4+1] + refb[idx*2+1]);
  float w  = sigmoidf_(t4[idx*4+2]);
  float h  = sigmoidf_(t4[idx*4+3]);
  int o = b*QLEN + q;
  boxes[o*4+0] = cx - 0.5f*w;
  boxes[o*4+1] = cy - 0.5f*h;
  boxes[o*4+2] = cx + 0.5f*w;
  boxes[o*4+3] = cy + 0.5f*h;
  cs[o] = cx + cy;
}

__global__ void bias_kernel(const float* __restrict__ boxes, const float* __restrict__ cs,
                            float* __restrict__ bias)
{
  int idx = blockIdx.x*blockDim.x + threadIdx.x;
  const int QQ = QLEN*QLEN;
  if (idx >= BATCH*QQ) return;
  int b = idx / QQ, rem = idx - b*QQ;
  int i = rem / QLEN, j = rem - i*QLEN;
  float4 bi = *reinterpret_cast<const float4*>(&boxes[((size_t)b*QLEN + i)*4]);
  float4 bj = *reinterpret_cast<const float4*>(&boxes[((size_t)b*QLEN + j)*4]);
  float ai = (bi.z-bi.x)*(bi.w-bi.y);
  float aj = (bj.z-bj.x)*(bj.w-bj.y);
  float ltx = fmaxf(bi.x, bj.x), lty = fmaxf(bi.y, bj.y);
  float rbx = fminf(bi.z, bj.z), rby = fminf(bi.w, bj.w);
  float w = fmaxf(rbx-ltx, 0.f), h = fmaxf(rby-lty, 0.f);
  float inter = w*h;
  float iou = inter / (ai + aj - inter);
  bias[idx] = iou + ((cs[b*QLEN+i] > cs[b*QLEN+j]) ? 1.f : 0.f);
}

__global__ void add_qp2(const float* __restrict__ X, const float* __restrict__ qp,
                        unsigned short* __restrict__ out)
{
  int idx = blockIdx.x*blockDim.x + threadIdx.x;
  if (idx >= NQROWS*DD) return;
  int r = idx >> 9, c = idx & 511;
  out[idx] = f2bf(X[idx] + qp[(r<<8) + (c & 255)]);
}

__global__ void caq_kernel(const float* __restrict__ X, const float* __restrict__ qp,
                           const float* __restrict__ sine, const float* __restrict__ pt,
                           unsigned short* __restrict__ out)
{
  int idx = blockIdx.x*blockDim.x + threadIdx.x;
  if (idx >= NQROWS*DD) return;
  int r = idx >> 9, c = idx & 511;
  int c2 = (r<<8) + (c & 255);
  out[idx] = f2bf(X[idx] + qp[c2] + sine[c2]*pt[c2]);
}

__global__ __launch_bounds__(256) void ln_residual(float* __restrict__ X, const float* __restrict__ Y,
                                                   unsigned short* __restrict__ Xb)
{
  int row = blockIdx.x, tid = threadIdx.x;
  size_t base = (size_t)row*DD;
  float v0 = X[base+tid]     + Y[base+tid];
  float v1 = X[base+tid+256] + Y[base+tid+256];
  float s = v0+v1, sq = v0*v0+v1*v1;
  for (int off = 32; off; off >>= 1) { s += __shfl_down(s,off); sq += __shfl_down(sq,off); }
  __shared__ float ss[4], ssq[4];
  int wid = tid>>6, lane = tid&63;
  if (lane==0){ ss[wid]=s; ssq[wid]=sq; }
  __syncthreads();
  if (tid==0){
    float a=ss[0]+ss[1]+ss[2]+ss[3], bsum=ssq[0]+ssq[1]+ssq[2]+ssq[3];
    float mean = a*(1.f/DD);
    float var  = bsum*(1.f/DD) - mean*mean;
    ss[0]=mean; ssq[0]=rsqrtf(fmaxf(var,0.f)+1e-5f);
  }
  __syncthreads();
  float mean = ss[0], inv = ssq[0];
  float o0 = (v0-mean)*inv, o1 = (v1-mean)*inv;
  X[base+tid]     = o0;  Xb[base+tid]     = f2bf(o0);
  X[base+tid+256] = o1;  Xb[base+tid+256] = f2bf(o1);
}

__global__ void init_x(const float* __restrict__ t, float* __restrict__ X,
                       unsigned short* __restrict__ Xb, int n)
{
  int idx = blockIdx.x*blockDim.x + threadIdx.x;
  if (idx < n){ float v = t[idx]; X[idx]=v; Xb[idx]=f2bf(v); }
}

__global__ void copy_f32(const float* __restrict__ src, float* __restrict__ dst, int n)
{
  int idx = blockIdx.x*blockDim.x + threadIdx.x;
  if (idx < n) dst[idx] = src[idx];
}

extern "C" void kernel_launch(void* const* d_in, const int* in_sizes, int n_in,
                              void* d_out, int out_size, void* d_ws, size_t ws_size,
                              hipStream_t stream)
{
  const float* tgt       = (const float*)d_in[0];
  const float* memory    = (const float*)d_in[1];
  const float* pos       = (const float*)d_in[2];
  const float* query_pos = (const float*)d_in[3];
  const float* qs_W1 = (const float*)d_in[4];  const float* qs_b1 = (const float*)d_in[5];
  const float* qs_W2 = (const float*)d_in[6];  const float* qs_b2 = (const float*)d_in[7];
  const float* rp_W1 = (const float*)d_in[8];  const float* rp_b1 = (const float*)d_in[9];
  const float* rp_W2 = (const float*)d_in[10]; const float* rp_b2 = (const float*)d_in[11];
  const float* bb_W1 = (const float*)d_in[12]; const float* bb_b1 = (const float*)d_in[13];
  const float* bb_W2 = (const float*)d_in[14]; const float* bb_b2 = (const float*)d_in[15];
  const float* sa_Wq = (const float*)d_in[16]; const float* sa_Wk = (const float*)d_in[17];
  const float* sa_Wv = (const float*)d_in[18]; const float* sa_Wo = (const float*)d_in[19];
  const float* ca_Wq = (const float*)d_in[20]; const float* ca_Wk = (const float*)d_in[21];
  const float* ca_Wv = (const float*)d_in[22]; const float* ca_Wo = (const float*)d_in[23];
  const float* ff_W1 = (const float*)d_in[24]; const float* ff_b1 = (const float*)d_in[25];
  const float* ff_W2 = (const float*)d_in[26]; const float* ff_b2 = (const float*)d_in[27];

  // ---------- workspace layout ----------
  float* F = (float*)d_ws;
  size_t o = 0;
  float* X    = F + o; o += (size_t)NQROWS*DD;
  float* RES  = F + o; o += (size_t)NQROWS*DD;
  float* SINE = F + o; o += (size_t)NQROWS*DM;
  float* PT   = F + o; o += (size_t)NQROWS*DM;
  float* BIAS = F + o; o += (size_t)BATCH*QLEN*QLEN;
  float* REFB = F + o; o += (size_t)NQROWS*2;
  float* T4   = F + o; o += (size_t)NQROWS*4;
  float* BOX  = F + o; o += (size_t)NQROWS*4;
  float* CS   = F + o; o += (size_t)NQROWS;
  float* T256 = RES;   // alias (lifetime-disjoint)
  unsigned short* U = (unsigned short*)(F + o);
  size_t u = 0;
  unsigned short* Xb   = U + u; u += (size_t)NQROWS*DD;
  unsigned short* QIN  = U + u; u += (size_t)NQROWS*DD;
  unsigned short* PQb  = U + u; u += (size_t)NQROWS*DD;
  unsigned short* PKb  = U + u; u += (size_t)NMROWS*DD;
  unsigned short* PVb  = U + u; u += (size_t)NMROWS*DD;
  unsigned short* T256b= U + u; u += (size_t)NQROWS*DM;
  unsigned short* WtSq = U + u; u += (size_t)6*DD*DD;
  unsigned short* WtSk = U + u; u += (size_t)6*DD*DD;
  unsigned short* WtSv = U + u; u += (size_t)6*DD*DD;
  unsigned short* WtSo = U + u; u += (size_t)6*DD*DD;
  unsigned short* WtCq = U + u; u += (size_t)6*DD*DD;
  unsigned short* WtCk = U + u; u += (size_t)6*DD*DD;
  unsigned short* WtCv = U + u; u += (size_t)6*DD*DD;
  unsigned short* WtCo = U + u; u += (size_t)6*DD*DD;
  unsigned short* WtF1 = U + u; u += (size_t)6*DD*FFND;
  unsigned short* WtF2 = U + u; u += (size_t)6*DD*FFND;
  unsigned short* WtQ1 = U + u; u += (size_t)DM*DM;
  unsigned short* WtQ2 = U + u; u += (size_t)DM*DM;
  unsigned short* AOb  = QIN;
  unsigned short* HIDb = PKb;
  if (ws_size < o*sizeof(float) + u*sizeof(unsigned short)) return;

  dim3 B256(256);
  const int nTotal = NQROWS*DD;

  // ---------- weight transpose+cvt ----------
  transpose_cvt<<<dim3(16,16,6), B256, 0, stream>>>(sa_Wq, WtSq, DD, DD);
  transpose_cvt<<<dim3(16,16,6), B256, 0, stream>>>(sa_Wk, WtSk, DD, DD);
  transpose_cvt<<<dim3(16,16,6), B256, 0, stream>>>(sa_Wv, WtSv, DD, DD);
  transpose_cvt<<<dim3(16,16,6), B256, 0, stream>>>(sa_Wo, WtSo, DD, DD);
  transpose_cvt<<<dim3(16,16,6), B256, 0, stream>>>(ca_Wq, WtCq, DD, DD);
  transpose_cvt<<<dim3(16,16,6), B256, 0, stream>>>(ca_Wk, WtCk, DD, DD);
  transpose_cvt<<<dim3(16,16,6), B256, 0, stream>>>(ca_Wv, WtCv, DD, DD);
  transpose_cvt<<<dim3(16,16,6), B256, 0, stream>>>(ca_Wo, WtCo, DD, DD);
  transpose_cvt<<<dim3(32,16,6), B256, 0, stream>>>(ff_W1, WtF1, DD, FFND);
  transpose_cvt<<<dim3(16,32,6), B256, 0, stream>>>(ff_W2, WtF2, FFND, DD);
  transpose_cvt<<<dim3(8,8,1),  B256, 0, stream>>>(qs_W1, WtQ1, DM, DM);
  transpose_cvt<<<dim3(8,8,1),  B256, 0, stream>>>(qs_W2, WtQ2, DM, DM);

  // ---------- pre-loop ----------
  init_x<<<dim3((nTotal+255)/256), B256, 0, stream>>>(tgt, X, Xb, nTotal);
  gemm_f32<<<dim3(DM/64, NQROWS/64), B256, 0, stream>>>(query_pos, nullptr, rp_W1, rp_b1, T256, NQROWS, DM, DM, DM, 1);
  gemm_skinny<<<dim3(NQROWS/4), B256, 0, stream>>>(T256, rp_W2, rp_b2, REFB, NQROWS, 2, DM, DM);
  sine_embed_kernel<<<dim3((NQROWS*DM+255)/256), B256, 0, stream>>>(REFB, SINE);

  for (int l = 0; l < 6; ++l) {
    const size_t wo = (size_t)l*DD*DD, fo = (size_t)l*DD*FFND;
    const float* fb1 = ff_b1 + (size_t)l*FFND;
    const float* fb2 = ff_b2 + (size_t)l*DD;

    // pos_transform MLP (bf16 MFMA; multiplicative modulation, accuracy-tolerant)
    gemm_mfma<1,true,true ><<<dim3(DM/64, NQROWS/64), B256, 0, stream>>>(X+DM, nullptr, WtQ1, qs_b1, T256b, NQROWS, DM, DM, DD);
    gemm_mfma<0,false,false><<<dim3(DM/64, NQROWS/64), B256, 0, stream>>>(T256b, nullptr, WtQ2, qs_b2, PT, NQROWS, DM, DM, DM);
    // bbox MLP -> boxes -> bias (f32: cs_i>cs_j comparison is flip-sensitive)
    gemm_f32<<<dim3(DM/64, NQROWS/64), B256, 0, stream>>>(X+DM, nullptr, bb_W1, bb_b1, T256, NQROWS, DM, DM, DD, 1);
    gemm_skinny<<<dim3(NQROWS/4), B256, 0, stream>>>(T256, bb_W2, bb_b2, T4, NQROWS, 4, DM, DM);
    boxes_kernel<<<dim3((NQROWS+255)/256), B256, 0, stream>>>(T4, REFB, BOX, CS);
    bias_kernel<<<dim3((BATCH*QLEN*QLEN+255)/256), B256, 0, stream>>>(BOX, CS, BIAS);

    // ---- self-attention ----
    add_qp2<<<dim3((nTotal+255)/256), B256, 0, stream>>>(X, query_pos, QIN);
    gemm2<64,0,true,false><<<dim3(DD/128, NQROWS/64), B256, 0, stream>>>(QIN, nullptr, WtSq+wo, nullptr, PQb, NQROWS, DD, DD, DD);
    gemm2<64,0,true,false><<<dim3(DD/128, NQROWS/64), B256, 0, stream>>>(QIN, nullptr, WtSk+wo, nullptr, PKb, NQROWS, DD, DD, DD);
    gemm2<64,0,true,false><<<dim3(DD/128, NQROWS/64), B256, 0, stream>>>(Xb,  nullptr, WtSv+wo, nullptr, PVb, NQROWS, DD, DD, DD);
    attn_mfma<true><<<dim3((QLEN+63)/64, BATCH*8), B256, 0, stream>>>(PQb, PKb, PVb, BIAS, AOb, QLEN, QLEN);
    gemm2<64,0,false,false><<<dim3(DD/128, NQROWS/64), B256, 0, stream>>>(AOb, nullptr, WtSo+wo, nullptr, RES, NQROWS, DD, DD, DD);
    ln_residual<<<dim3(NQROWS), B256, 0, stream>>>(X, RES, Xb);

    // ---- cross-attention ----
    caq_kernel<<<dim3((nTotal+255)/256), B256, 0, stream>>>(X, query_pos, SINE, PT, QIN);
    gemm2<64,0,true,false><<<dim3(DD/128, NQROWS/64), B256, 0, stream>>>(QIN, nullptr, WtCq+wo, nullptr, PQb, NQROWS, DD, DD, DD);
    gemm2<128,2,true,false><<<dim3(DD/128, NMROWS/128), B256, 0, stream>>>(memory, pos, WtCk+wo, nullptr, PKb, NMROWS, DD, DD, DD);
    gemm2<128,1,true,false><<<dim3(DD/128, NMROWS/128), B256, 0, stream>>>(memory, nullptr, WtCv+wo, nullptr, PVb, NMROWS, DD, DD, DD);
    attn_mfma<false><<<dim3((QLEN+63)/64, BATCH*8), B256, 0, stream>>>(PQb, PKb, PVb, nullptr, AOb, QLEN, SLEN);
    gemm2<64,0,false,false><<<dim3(DD/128, NQROWS/64), B256, 0, stream>>>(AOb, nullptr, WtCo+wo, nullptr, RES, NQROWS, DD, DD, DD);
    ln_residual<<<dim3(NQROWS), B256, 0, stream>>>(X, RES, Xb);

    // ---- FFN ----
    gemm2<64,0,true,true ><<<dim3(FFND/128, NQROWS/64), B256, 0, stream>>>(Xb, nullptr, WtF1+fo, fb1, HIDb, NQROWS, FFND, DD, DD);
    gemm2<64,0,false,false><<<dim3(DD/128, NQROWS/64), B256, 0, stream>>>(HIDb, nullptr, WtF2+fo, fb2, RES, NQROWS, DD, FFND, FFND);
    ln_residual<<<dim3(NQROWS), B256, 0, stream>>>(X, RES, Xb);
  }

  copy_f32<<<dim3((nTotal+255)/256), B256, 0, stream>>>(X, (float*)d_out, out_size);
}